// Round 6
// baseline (119.980 us; speedup 1.0000x reference)
//
#include <hip/hip_runtime.h>
#include <math.h>

#define N_V 12288
#define D_F 32
#define N_E 196608
#define KNN 6
#define EPSF 1e-12f

#define SEGS 24
#define JSEG (N_V / SEGS)          // 512 candidate columns per segment
#define SUBTILES (JSEG / 16)       // 32 j-subtiles per segment
#define GROUP 2                    // subtiles per pipeline group
#define NGROUPS (SUBTILES / GROUP) // 16
#define ROWS_PER_BLOCK 128         // 4 waves x 32 query rows
#define ROW_BLOCKS (N_V / ROWS_PER_BLOCK)   // 96
#define TOPK_BLOCKS (ROW_BLOCKS * SEGS)     // 2304
#define EDGE_BLOCKS (N_E / 256)             // 768

typedef __bf16 bf16x8 __attribute__((ext_vector_type(8)));
typedef float f32x4 __attribute__((ext_vector_type(4)));

static_assert(N_V % ROWS_PER_BLOCK == 0, "");
static_assert(SUBTILES % GROUP == 0, "");

__device__ __forceinline__ unsigned short f2bf(float f) {
    unsigned u = __builtin_bit_cast(unsigned, f);
    unsigned r = u + 0x7fffu + ((u >> 16) & 1u);   // RNE
    return (unsigned short)(r >> 16);
}

// descending sorted 6-list insert: 1 max + 5 med3
__device__ __forceinline__ void ins6(float s[KNN], float nv) {
    float y0 = fmaxf(s[0], nv);
    float y1 = __builtin_amdgcn_fmed3f(s[0], s[1], nv);
    float y2 = __builtin_amdgcn_fmed3f(s[1], s[2], nv);
    float y3 = __builtin_amdgcn_fmed3f(s[2], s[3], nv);
    float y4 = __builtin_amdgcn_fmed3f(s[3], s[4], nv);
    float y5 = __builtin_amdgcn_fmed3f(s[4], s[5], nv);
    s[0] = y0; s[1] = y1; s[2] = y2; s[3] = y3; s[4] = y4; s[5] = y5;
}

// ---------- kernel 0: bf16 convert + msq(-0.5*sq), 8 threads/row ----------
__global__ __launch_bounds__(256) void prep_kernel(const float* __restrict__ x,
                                                   unsigned short* __restrict__ xb,
                                                   float* __restrict__ msq) {
    const int gid = blockIdx.x * 256 + threadIdx.x;   // 0..98303
    const int row = gid >> 3;
    const int h = gid & 7;
    float4 p = ((const float4*)(x + (size_t)row * D_F))[h];
    float s = p.x * p.x + p.y * p.y + p.z * p.z + p.w * p.w;
    s += __shfl_xor(s, 1, 64);
    s += __shfl_xor(s, 2, 64);
    s += __shfl_xor(s, 4, 64);
    const unsigned lo = (unsigned)f2bf(p.x) | ((unsigned)f2bf(p.y) << 16);
    const unsigned hi = (unsigned)f2bf(p.z) | ((unsigned)f2bf(p.w) << 16);
    ((uint2*)xb)[gid] = make_uint2(lo, hi);
    if (h == 0) msq[row] = -0.5f * s;
}

// ---------- kernel 1: MFMA gram top-6 (blocks [0,TOPK)) + edge-ey (rest) ----------
// A = candidate rows (j), B = query rows (i). C[m=quad*4+reg][n=l16]:
// lane's query row = rowbase + rt*16 + l16, candidates j = col0 + quad*4 + reg.
// acc init = msq[j] => C = dot - 0.5*sq_j (selection key; larger == closer).
__global__ __launch_bounds__(256, 6) void topk_mfma(
    const unsigned short* __restrict__ xb, const float* __restrict__ msq,
    float* __restrict__ cand, const float* __restrict__ x,
    const int* __restrict__ ei, float* __restrict__ out) {
    const int t = threadIdx.x;

    if (blockIdx.x >= TOPK_BLOCKS) {
        // ---- edge-ey path: out[.,1] = 1 - exp(-||x_u - x_w||) ----
        const int e = (blockIdx.x - TOPK_BLOCKS) * 256 + t;
        const int u = ei[e];
        const int w = ei[N_E + e];
        const float4* xu = (const float4*)(x + (size_t)u * D_F);
        const float4* xw = (const float4*)(x + (size_t)w * D_F);
        float a0 = 0.f, a1 = 0.f, a2 = 0.f, a3 = 0.f;
#pragma unroll
        for (int d = 0; d < 8; ++d) {
            float4 p = xu[d], q = xw[d];
            float dx = p.x - q.x, dy = p.y - q.y, dz = p.z - q.z, dw = p.w - q.w;
            a0 += dx * dx; a1 += dy * dy; a2 += dz * dz; a3 += dw * dw;
        }
        const float enorm = sqrtf(fmaxf((a0 + a1) + (a2 + a3), EPSF));
        out[2 * (N_V + e) + 1] = 1.0f - expf(-enorm);
        return;
    }

    const int wave = t >> 6;
    const int lane = t & 63;
    const int quad = lane >> 4;
    const int l16 = lane & 15;

    const int seg = blockIdx.x / ROW_BLOCKS;          // consecutive blocks share seg (L2)
    const int rb = blockIdx.x % ROW_BLOCKS;
    const int rowbase = rb * ROWS_PER_BLOCK + wave * 32;
    const int j0 = seg * JSEG;

    // B fragments: query rows, register-resident
    bf16x8 bfrag[2];
#pragma unroll
    for (int rt = 0; rt < 2; ++rt)
        bfrag[rt] = *reinterpret_cast<const bf16x8*>(
            xb + (size_t)(rowbase + rt * 16 + l16) * D_F + quad * 8);

    float tk[2][KNN];
#pragma unroll
    for (int rt = 0; rt < 2; ++rt)
#pragma unroll
        for (int k = 0; k < KNN; ++k) tk[rt][k] = -3.0e38f;

    const unsigned short* aptr = xb + (size_t)(j0 + l16) * D_F + quad * 8;
    const float* mptr = msq + j0 + quad * 4;

    // ---- depth-2-group double-buffered register pipeline ----
    bf16x8 abuf[2][GROUP];
    float4 mbuf[2][GROUP];
#pragma unroll
    for (int u = 0; u < GROUP; ++u) {
        abuf[0][u] = *reinterpret_cast<const bf16x8*>(aptr + u * (16 * D_F));
        mbuf[0][u] = *reinterpret_cast<const float4*>(mptr + u * 16);
    }
    for (int g = 0; g < NGROUPS; ++g) {
        const int cur = g & 1, nb = cur ^ 1;
        if (g + 1 < NGROUPS) {
            const unsigned short* ap = aptr + (size_t)(g + 1) * (GROUP * 16 * D_F);
            const float* mp = mptr + (g + 1) * (GROUP * 16);
#pragma unroll
            for (int u = 0; u < GROUP; ++u) {
                abuf[nb][u] = *reinterpret_cast<const bf16x8*>(ap + u * (16 * D_F));
                mbuf[nb][u] = *reinterpret_cast<const float4*>(mp + u * 16);
            }
        }
#pragma unroll
        for (int u = 0; u < GROUP; ++u) {
            const float4 m = mbuf[cur][u];
            const f32x4 cinit = {m.x, m.y, m.z, m.w};
#pragma unroll
            for (int rt = 0; rt < 2; ++rt) {
                f32x4 c = __builtin_amdgcn_mfma_f32_16x16x32_bf16(abuf[cur][u], bfrag[rt], cinit, 0, 0, 0);
#pragma unroll
                for (int reg = 0; reg < 4; ++reg)
                    ins6(tk[rt], c[reg]);
            }
        }
    }

    // ---- cross-quad merge via shuffles (row's lists live in 4 quads, same l16) ----
#pragma unroll
    for (int rt = 0; rt < 2; ++rt) {
#pragma unroll
        for (int rnd = 0; rnd < 2; ++rnd) {
            const int mask = 16 << rnd;
            float b[KNN];
#pragma unroll
            for (int k = 0; k < KNN; ++k) b[k] = __shfl_xor(tk[rt][k], mask, 64);
#pragma unroll
            for (int k = 0; k < KNN; ++k) ins6(tk[rt], b[k]);
        }
    }

    if (quad == 0) {
#pragma unroll
        for (int rt = 0; rt < 2; ++rt) {
            const int g = rowbase + rt * 16 + l16;
            float* dst = cand + ((size_t)g * SEGS + seg) * KNN;
#pragma unroll
            for (int k = 0; k < KNN; ++k) dst[k] = tk[rt][k];
        }
    }
}

// ---------- kernel 2: merge per-segment keys -> v, 4 threads/row ----------
__global__ __launch_bounds__(256) void merge_v(const float* __restrict__ cand,
                                               const float* __restrict__ msq,
                                               float* __restrict__ v,
                                               float* __restrict__ out) {
    const int gid = blockIdx.x * 256 + threadIdx.x;   // 0..49151
    const int row = gid >> 2;
    const int h = gid & 3;
    const float4* c = (const float4*)(cand + (size_t)row * (SEGS * KNN));  // 36 x float4
    float mk[KNN];
#pragma unroll
    for (int k = 0; k < KNN; ++k) mk[k] = -3.0e38f;
#pragma unroll
    for (int s4 = 0; s4 < (SEGS * KNN / 4) / 4; ++s4) {   // 9 each
        float4 q = c[s4 * 4 + h];
        ins6(mk, q.x); ins6(mk, q.y); ins6(mk, q.z); ins6(mk, q.w);
    }
    // merge across the 4 lanes of this row (consecutive lanes, same wave)
#pragma unroll
    for (int rnd = 0; rnd < 2; ++rnd) {
        const int mask = 1 << rnd;
        float b[KNN];
#pragma unroll
        for (int k = 0; k < KNN; ++k) b[k] = __shfl_xor(mk[k], mask, 64);
#pragma unroll
        for (int k = 0; k < KNN; ++k) ins6(mk, b[k]);
    }
    if (h == 0) {
        const float msqi = msq[row];
        float ssum = 0.f;
#pragma unroll
        for (int m = 1; m < KNN; ++m) {
            const float d2 = -2.0f * (mk[m] + msqi);   // sq_i - 2*key
            ssum += expf(-sqrtf(fmaxf(d2, EPSF)));
        }
        const float vi = 1.0f - ssum / (float)KNN;
        v[row] = vi;
        out[2 * row] = vi;
        out[2 * row + 1] = 0.0f;
    }
}

// ---------- kernel 3: edge value = max(v[u], v[w]) ----------
__global__ __launch_bounds__(256) void edge_val(const int* __restrict__ ei,
                                                const float* __restrict__ v,
                                                float* __restrict__ out) {
    const int e = blockIdx.x * 256 + threadIdx.x;
    const int u = ei[e];
    const int w = ei[N_E + e];
    out[2 * (N_V + e) + 0] = fmaxf(v[u], v[w]);
}

extern "C" void kernel_launch(void* const* d_in, const int* in_sizes, int n_in,
                              void* d_out, int out_size, void* d_ws, size_t ws_size,
                              hipStream_t stream) {
    const float* x = (const float*)d_in[0];
    const int* ei = (const int*)d_in[1];
    float* out = (float*)d_out;
    char* ws = (char*)d_ws;

    unsigned short* xb = (unsigned short*)ws;                  // 786432 B
    float* msq = (float*)(ws + 786432);                        // 49152 B
    float* v   = (float*)(ws + 786432 + 49152);                // 49152 B
    float* cand = (float*)(ws + 786432 + 2 * 49152);           // 7077888 B (~7.96 MB total)

    prep_kernel<<<(N_V * 8) / 256, 256, 0, stream>>>(x, xb, msq);

    topk_mfma<<<TOPK_BLOCKS + EDGE_BLOCKS, 256, 0, stream>>>(xb, msq, cand, x, ei, out);

    merge_v<<<(N_V * 4) / 256, 256, 0, stream>>>(cand, msq, v, out);

    edge_val<<<N_E / 256, 256, 0, stream>>>(ei, v, out);
}

// Round 7
// 115.499 us; speedup vs baseline: 1.0388x; 1.0388x over previous
//
#include <hip/hip_runtime.h>
#include <math.h>

#define N_V 12288
#define D_F 32
#define N_E 196608
#define KNN 6
#define EPSF 1e-12f

#define SEGS 24
#define JSEG (N_V / SEGS)          // 512 candidate columns per segment
#define SUBTILES (JSEG / 16)       // 32 j-subtiles per segment
#define ROWS_PER_BLOCK 128         // 4 waves x 32 query rows
#define ROW_BLOCKS (N_V / ROWS_PER_BLOCK)   // 96
#define TOPK_BLOCKS (ROW_BLOCKS * SEGS)     // 2304
#define EDGE_BLOCKS (N_E / 256)             // 768

typedef __bf16 bf16x8 __attribute__((ext_vector_type(8)));
typedef float f32x4 __attribute__((ext_vector_type(4)));

static_assert(N_V % ROWS_PER_BLOCK == 0, "");
static_assert(SUBTILES % 4 == 0, "");

__device__ __forceinline__ unsigned short f2bf(float f) {
    unsigned u = __builtin_bit_cast(unsigned, f);
    unsigned r = u + 0x7fffu + ((u >> 16) & 1u);   // RNE
    return (unsigned short)(r >> 16);
}

// descending sorted 6-list insert: 1 max + 5 med3
__device__ __forceinline__ void ins6(float s[KNN], float nv) {
    float y0 = fmaxf(s[0], nv);
    float y1 = __builtin_amdgcn_fmed3f(s[0], s[1], nv);
    float y2 = __builtin_amdgcn_fmed3f(s[1], s[2], nv);
    float y3 = __builtin_amdgcn_fmed3f(s[2], s[3], nv);
    float y4 = __builtin_amdgcn_fmed3f(s[3], s[4], nv);
    float y5 = __builtin_amdgcn_fmed3f(s[4], s[5], nv);
    s[0] = y0; s[1] = y1; s[2] = y2; s[3] = y3; s[4] = y4; s[5] = y5;
}

// ---------- kernel 0: bf16 convert + msq(-0.5*sq), 8 threads/row ----------
__global__ __launch_bounds__(256) void prep_kernel(const float* __restrict__ x,
                                                   unsigned short* __restrict__ xb,
                                                   float* __restrict__ msq) {
    const int gid = blockIdx.x * 256 + threadIdx.x;   // 0..98303
    const int row = gid >> 3;
    const int h = gid & 7;
    float4 p = ((const float4*)(x + (size_t)row * D_F))[h];
    float s = p.x * p.x + p.y * p.y + p.z * p.z + p.w * p.w;
    s += __shfl_xor(s, 1, 64);
    s += __shfl_xor(s, 2, 64);
    s += __shfl_xor(s, 4, 64);
    const unsigned lo = (unsigned)f2bf(p.x) | ((unsigned)f2bf(p.y) << 16);
    const unsigned hi = (unsigned)f2bf(p.z) | ((unsigned)f2bf(p.w) << 16);
    ((uint2*)xb)[gid] = make_uint2(lo, hi);
    if (h == 0) msq[row] = -0.5f * s;
}

// ---------- kernel 1: edge-ey (blocks [0,EDGE)) + MFMA gram top-6 (rest) ----------
// A = candidate rows (j), B = query rows (i). C[m=quad*4+reg][n=l16]:
// lane's query row = rowbase + rt*16 + l16, candidates j = col0 + quad*4 + reg.
// acc init = msq[j] => C = dot - 0.5*sq_j (selection key; larger == closer).
__global__ __launch_bounds__(256, 8) void topk_mfma(
    const unsigned short* __restrict__ xb, const float* __restrict__ msq,
    float* __restrict__ cand, const float* __restrict__ x,
    const int* __restrict__ ei, float* __restrict__ out) {
    const int t = threadIdx.x;

    if (blockIdx.x < EDGE_BLOCKS) {
        // ---- edge-ey path: out[.,1] = 1 - exp(-||x_u - x_w||) ----
        const int e = blockIdx.x * 256 + t;
        const int u = ei[e];
        const int w = ei[N_E + e];
        const float4* xu = (const float4*)(x + (size_t)u * D_F);
        const float4* xw = (const float4*)(x + (size_t)w * D_F);
        float a0 = 0.f, a1 = 0.f, a2 = 0.f, a3 = 0.f;
#pragma unroll
        for (int d = 0; d < 8; ++d) {
            float4 p = xu[d], q = xw[d];
            float dx = p.x - q.x, dy = p.y - q.y, dz = p.z - q.z, dw = p.w - q.w;
            a0 += dx * dx; a1 += dy * dy; a2 += dz * dz; a3 += dw * dw;
        }
        const float enorm = sqrtf(fmaxf((a0 + a1) + (a2 + a3), EPSF));
        out[2 * (N_V + e) + 1] = 1.0f - expf(-enorm);
        return;
    }

    const int wave = t >> 6;
    const int lane = t & 63;
    const int quad = lane >> 4;
    const int l16 = lane & 15;

    const int bid = blockIdx.x - EDGE_BLOCKS;
    const int rb = bid % ROW_BLOCKS;
    const int seg = bid / ROW_BLOCKS;
    const int rowbase = rb * ROWS_PER_BLOCK + wave * 32;
    const int j0 = seg * JSEG;

    // B fragments: query rows, register-resident
    bf16x8 bfrag[2];
#pragma unroll
    for (int rt = 0; rt < 2; ++rt)
        bfrag[rt] = *reinterpret_cast<const bf16x8*>(
            xb + (size_t)(rowbase + rt * 16 + l16) * D_F + quad * 8);

    float tk[2][KNN];
#pragma unroll
    for (int rt = 0; rt < 2; ++rt)
#pragma unroll
        for (int k = 0; k < KNN; ++k) tk[rt][k] = -3.0e38f;

    const unsigned short* aptr = xb + (size_t)(j0 + l16) * D_F + quad * 8;
    const float* mptr = msq + j0 + quad * 4;

    for (int it = 0; it < SUBTILES; it += 4) {
#pragma unroll
        for (int u = 0; u < 4; ++u) {
            const bf16x8 a = *reinterpret_cast<const bf16x8*>(aptr + u * (16 * D_F));
            const float4 m = *reinterpret_cast<const float4*>(mptr + u * 16);
            const f32x4 cinit = {m.x, m.y, m.z, m.w};
#pragma unroll
            for (int rt = 0; rt < 2; ++rt) {
                f32x4 c = __builtin_amdgcn_mfma_f32_16x16x32_bf16(a, bfrag[rt], cinit, 0, 0, 0);
#pragma unroll
                for (int reg = 0; reg < 4; ++reg)
                    ins6(tk[rt], c[reg]);
            }
        }
        aptr += 4 * 16 * D_F;
        mptr += 4 * 16;
    }

    // ---- cross-quad merge via shuffles (row's lists live in 4 quads, same l16) ----
#pragma unroll
    for (int rt = 0; rt < 2; ++rt) {
#pragma unroll
        for (int rnd = 0; rnd < 2; ++rnd) {
            const int mask = 16 << rnd;
            float b[KNN];
#pragma unroll
            for (int k = 0; k < KNN; ++k) b[k] = __shfl_xor(tk[rt][k], mask, 64);
#pragma unroll
            for (int k = 0; k < KNN; ++k) ins6(tk[rt], b[k]);
        }
    }

    if (quad == 0) {
#pragma unroll
        for (int rt = 0; rt < 2; ++rt) {
            const int g = rowbase + rt * 16 + l16;
            float* dst = cand + ((size_t)g * SEGS + seg) * KNN;
#pragma unroll
            for (int k = 0; k < KNN; ++k) dst[k] = tk[rt][k];
        }
    }
}

// ---------- kernel 2: merge per-segment keys -> v, 4 threads/row ----------
__global__ __launch_bounds__(256) void merge_v(const float* __restrict__ cand,
                                               const float* __restrict__ msq,
                                               float* __restrict__ v,
                                               float* __restrict__ out) {
    const int gid = blockIdx.x * 256 + threadIdx.x;   // 0..49151
    const int row = gid >> 2;
    const int h = gid & 3;
    const float4* c = (const float4*)(cand + (size_t)row * (SEGS * KNN));  // 36 x float4
    float mk[KNN];
#pragma unroll
    for (int k = 0; k < KNN; ++k) mk[k] = -3.0e38f;
#pragma unroll
    for (int s4 = 0; s4 < (SEGS * KNN / 4) / 4; ++s4) {   // 9 each
        float4 q = c[s4 * 4 + h];
        ins6(mk, q.x); ins6(mk, q.y); ins6(mk, q.z); ins6(mk, q.w);
    }
    // merge across the 4 lanes of this row (consecutive lanes, same wave)
#pragma unroll
    for (int rnd = 0; rnd < 2; ++rnd) {
        const int mask = 1 << rnd;
        float b[KNN];
#pragma unroll
        for (int k = 0; k < KNN; ++k) b[k] = __shfl_xor(mk[k], mask, 64);
#pragma unroll
        for (int k = 0; k < KNN; ++k) ins6(mk, b[k]);
    }
    if (h == 0) {
        const float msqi = msq[row];
        float ssum = 0.f;
#pragma unroll
        for (int m = 1; m < KNN; ++m) {
            const float d2 = -2.0f * (mk[m] + msqi);   // sq_i - 2*key
            ssum += expf(-sqrtf(fmaxf(d2, EPSF)));
        }
        const float vi = 1.0f - ssum / (float)KNN;
        v[row] = vi;
        out[2 * row] = vi;
        out[2 * row + 1] = 0.0f;
    }
}

// ---------- kernel 3: edge value = max(v[u], v[w]) ----------
__global__ __launch_bounds__(256) void edge_val(const int* __restrict__ ei,
                                                const float* __restrict__ v,
                                                float* __restrict__ out) {
    const int e = blockIdx.x * 256 + threadIdx.x;
    const int u = ei[e];
    const int w = ei[N_E + e];
    out[2 * (N_V + e) + 0] = fmaxf(v[u], v[w]);
}

extern "C" void kernel_launch(void* const* d_in, const int* in_sizes, int n_in,
                              void* d_out, int out_size, void* d_ws, size_t ws_size,
                              hipStream_t stream) {
    const float* x = (const float*)d_in[0];
    const int* ei = (const int*)d_in[1];
    float* out = (float*)d_out;
    char* ws = (char*)d_ws;

    unsigned short* xb = (unsigned short*)ws;                  // 786432 B
    float* msq = (float*)(ws + 786432);                        // 49152 B
    float* v   = (float*)(ws + 786432 + 49152);                // 49152 B
    float* cand = (float*)(ws + 786432 + 2 * 49152);           // 7077888 B (~7.97 MB total)

    prep_kernel<<<(N_V * 8) / 256, 256, 0, stream>>>(x, xb, msq);

    topk_mfma<<<EDGE_BLOCKS + TOPK_BLOCKS, 256, 0, stream>>>(xb, msq, cand, x, ei, out);

    merge_v<<<(N_V * 4) / 256, 256, 0, stream>>>(cand, msq, v, out);

    edge_val<<<N_E / 256, 256, 0, stream>>>(ei, v, out);
}